// Round 21
// baseline (174.079 us; speedup 1.0000x reference)
//
#include <hip/hip_runtime.h>
#include <cstdint>
#include <cstddef>

typedef __attribute__((ext_vector_type(4))) float f32x4;
typedef __attribute__((ext_vector_type(8))) short s16x8;
typedef __attribute__((ext_vector_type(4))) short s16x4;
typedef __attribute__((ext_vector_type(4))) int i32x4;

#define DEV __device__ __forceinline__

DEV short f2bf(float f) {
    unsigned u = __builtin_bit_cast(unsigned, f);
    unsigned r = (u + 0x7FFFu + ((u >> 16) & 1u)) >> 16;
    return (short)r;
}

DEV float bf2f(short s) {
    return __builtin_bit_cast(float, ((unsigned)(unsigned short)s) << 16);
}

DEV void gload_lds16(const void* g, void* l) {
    __builtin_amdgcn_global_load_lds(
        (const __attribute__((address_space(1))) unsigned int*)g,
        (__attribute__((address_space(3))) unsigned int*)l, 16, 0, 0);
}

// ---------------- conversion / packing kernels ----------------

__global__ void k_cvt_x(const float* __restrict__ X, short* __restrict__ Xb, int n4) {
    int stride = gridDim.x * blockDim.x;
    for (int i = blockIdx.x * blockDim.x + threadIdx.x; i < n4; i += stride) {
        f32x4 v = *(const f32x4*)&X[i * 4];
        s16x4 s;
#pragma unroll
        for (int j = 0; j < 4; ++j) s[j] = f2bf(v[j]);
        *(s16x4*)&Xb[i * 4] = s;
    }
}

// Coalesced LDS-transpose pack: Wbt[t*1024+h*64+k][d] = W_t[h][d][k].
__global__ void k_pack_wqkv_t(const float* __restrict__ Wq, const float* __restrict__ Wk,
                              const float* __restrict__ Wv, short* __restrict__ Wbt) {
    __shared__ float tileT[64][65];   // [k][d], +1 pad
    const int bx = blockIdx.x, tid = threadIdx.x;
    const int t = bx >> 8, h = (bx >> 4) & 15, dc = bx & 15;
    const float* W = (t == 0) ? Wq : (t == 1) ? Wk : Wv;
    const float* src = W + ((size_t)h * 1024 + dc * 64) * 64;   // contiguous 4096 f32
#pragma unroll
    for (int i = 0; i < 4; ++i) {
        int idx4 = i * 256 + tid;
        f32x4 v = *(const f32x4*)&src[idx4 * 4];
        int flat = idx4 * 4;
        int d = flat >> 6, k0 = flat & 63;
#pragma unroll
        for (int q = 0; q < 4; ++q) tileT[k0 + q][d] = v[q];
    }
    __syncthreads();
    const int k = tid >> 2, d4 = (tid & 3) * 16;
    s16x8 o0, o1;
#pragma unroll
    for (int q = 0; q < 8; ++q) {
        o0[q] = f2bf(tileT[k][d4 + q]);
        o1[q] = f2bf(tileT[k][d4 + 8 + q]);
    }
    size_t c = (size_t)t * 1024 + h * 64 + k;
    *(s16x8*)&Wbt[c * 1024 + dc * 64 + d4] = o0;
    *(s16x8*)&Wbt[c * 1024 + dc * 64 + d4 + 8] = o1;
}

// Coalesced transpose pack: Wobt[n][c] = Wo[c][n]. grid 256 = cchunk x nchunk.
__global__ void k_pack_wo_t(const float* __restrict__ Wo, short* __restrict__ Wobt) {
    __shared__ float tileT[64][65];   // [n][c]
    const int bx = blockIdx.x, tid = threadIdx.x;
    const int c0 = (bx >> 4) * 64, n0 = (bx & 15) * 64;
    const int r = tid >> 2, cch = tid & 3;
#pragma unroll
    for (int it = 0; it < 4; ++it) {
        int colf = cch * 4 + it * 16;
        f32x4 v = *(const f32x4*)&Wo[(size_t)(c0 + r) * 1024 + n0 + colf];
#pragma unroll
        for (int q = 0; q < 4; ++q) tileT[colf + q][r] = v[q];
    }
    __syncthreads();
    const int n = tid >> 2, c4 = (tid & 3) * 16;
    s16x8 o0, o1;
#pragma unroll
    for (int q = 0; q < 8; ++q) {
        o0[q] = f2bf(tileT[n][c4 + q]);
        o1[q] = f2bf(tileT[n][c4 + 8 + q]);
    }
    *(s16x8*)&Wobt[(size_t)(n0 + n) * 1024 + c0 + c4] = o0;
    *(s16x8*)&Wobt[(size_t)(n0 + n) * 1024 + c0 + c4 + 8] = o1;
}

// ---------------- GEMM (128x128, 4 waves): used for the output projection ----

template <int EPI>
__launch_bounds__(256)
__global__ void gemm_bf16(const short* __restrict__ Ag, const short* __restrict__ Btg,
                          const float* __restrict__ b0, const float* __restrict__ b1,
                          const float* __restrict__ b2,
                          short* __restrict__ O0, short* __restrict__ O1, short* __restrict__ O2,
                          float* __restrict__ Of) {
    __shared__ short As[128 * 64];
    __shared__ short Bs[128 * 64];
    const int tid = threadIdx.x;
    const int wave = tid >> 6, lane = tid & 63;
    const int wm = wave >> 1, wn = wave & 1;
    const int m0 = blockIdx.y * 128, n0 = blockIdx.x * 128;

    f32x4 acc[4][4] = {};

    const int lr = lane >> 3;
    const int cb = (lane & 7) * 16;
    const int cl = cb ^ (lr << 4);

    for (int kt = 0; kt < 16; ++kt) {
        __syncthreads();
#pragma unroll
        for (int i = 0; i < 4; ++i) {
            int r8 = wave * 32 + i * 8;
            const char* ga = (const char*)(Ag + (size_t)(m0 + r8 + lr) * 1024 + kt * 64) + cl;
            gload_lds16(ga, &As[r8 * 64]);
            const char* gb = (const char*)(Btg + (size_t)(n0 + r8 + lr) * 1024 + kt * 64) + cl;
            gload_lds16(gb, &Bs[r8 * 64]);
        }
        asm volatile("s_waitcnt vmcnt(0)" ::: "memory");
        __syncthreads();
#pragma unroll
        for (int ks = 0; ks < 2; ++ks) {
            int kb = ks * 64 + (lane >> 4) * 16;
            s16x8 af[4], bf[4];
#pragma unroll
            for (int mf = 0; mf < 4; ++mf) {
                int m = wm * 64 + mf * 16 + (lane & 15);
                af[mf] = *(const s16x8*)&As[m * 64 + ((kb ^ ((m & 7) << 4)) >> 1)];
            }
#pragma unroll
            for (int nf = 0; nf < 4; ++nf) {
                int n = wn * 64 + nf * 16 + (lane & 15);
                bf[nf] = *(const s16x8*)&Bs[n * 64 + ((kb ^ ((n & 7) << 4)) >> 1)];
            }
#pragma unroll
            for (int mf = 0; mf < 4; ++mf)
#pragma unroll
                for (int nf = 0; nf < 4; ++nf)
                    acc[mf][nf] = __builtin_amdgcn_mfma_f32_16x16x32_bf16(af[mf], bf[nf],
                                                                          acc[mf][nf], 0, 0, 0);
        }
    }

    if (EPI == 0) {
#pragma unroll
        for (int nf = 0; nf < 4; ++nf) {
            int n = n0 + wn * 64 + nf * 16 + (lane & 15);
            int t = n >> 10;
            int h = (n >> 6) & 15;
            int kk = n & 63;
            const float* bias = (t == 0) ? b0 : (t == 1) ? b1 : b2;
            short* dst = (t == 0) ? O0 : (t == 1) ? O1 : O2;
            float scale = (t == 0) ? 0.1803368851f : 1.0f;
            float bb = bias[h * 64 + kk];
#pragma unroll
            for (int mf = 0; mf < 4; ++mf) {
#pragma unroll
                for (int r = 0; r < 4; ++r) {
                    int m = m0 + wm * 64 + mf * 16 + (lane >> 4) * 4 + r;
                    int b_ = m >> 11, sp = m & 2047;
                    float v = (acc[mf][nf][r] + bb) * scale;
                    dst[(((size_t)(b_ * 16 + h)) * 2048 + sp) * 64 + kk] = f2bf(v);
                }
            }
        }
    } else {
#pragma unroll
        for (int nf = 0; nf < 4; ++nf) {
            int n = n0 + wn * 64 + nf * 16 + (lane & 15);
            float bb = b0[n];
#pragma unroll
            for (int mf = 0; mf < 4; ++mf) {
#pragma unroll
                for (int r = 0; r < 4; ++r) {
                    int m = m0 + wm * 64 + mf * 16 + (lane >> 4) * 4 + r;
                    Of[(size_t)m * 1024 + n] = acc[mf][nf][r] + bb;
                }
            }
        }
    }
}

// ---------------- QKV GEMM: 256x128 tile, 512 threads (8 waves, 4m x 2n) ----
// ROUND-21: XCD-aware block swizzle (T1): 768 blocks, 768%8==0 -> bijective
// chunked swizzle gives each XCD 96 consecutive work items = 4 full y-rows,
// so the 24 x-blocks sharing one 512KB A-tile hit the SAME per-XCD L2
// (4 tiles x 512KB = 2MB < 4MB). Work mapping only; correctness-neutral.
// V-region blocks (n0 >= 2048) transpose output through LDS -> coalesced
// VtG[h][v][s] rows (round 20). NO min-waves clamp (spilled 3x).

__launch_bounds__(512)
__global__ void gemm_qkv(const short* __restrict__ Ag, const short* __restrict__ Btg,
                         const float* __restrict__ b0, const float* __restrict__ b1,
                         const float* __restrict__ b2,
                         short* __restrict__ O0, short* __restrict__ O1,
                         short* __restrict__ O2) {
    __shared__ short SMEM[256 * 64 + 128 * 64];   // 48 KB: As | Bs
    short* As = SMEM;
    short* Bs = SMEM + 256 * 64;
    const int tid = threadIdx.x;
    const int wave = tid >> 6, lane = tid & 63;
    const int wm = wave >> 1, wn = wave & 1;   // 4m x 2n
    // XCD swizzle: linear id -> (xcd gets 96 consecutive work items)
    const int bid = blockIdx.x + 24 * blockIdx.y;          // 0..767
    const int sb = (bid & 7) * 96 + (bid >> 3);            // bijective (768%8==0)
    const int m0 = (sb / 24) * 256, n0 = (sb % 24) * 128;

    f32x4 acc[4][4] = {};

    const int lr = lane >> 3;
    const int cb = (lane & 7) * 16;
    const int cl = cb ^ (lr << 4);

    for (int kt = 0; kt < 16; ++kt) {
        __syncthreads();
#pragma unroll
        for (int i = 0; i < 4; ++i) {
            int r8 = i * 64 + wave * 8;
            const char* ga = (const char*)(Ag + (size_t)(m0 + r8 + lr) * 1024 + kt * 64) + cl;
            gload_lds16(ga, &As[r8 * 64]);
        }
#pragma unroll
        for (int i = 0; i < 2; ++i) {
            int r8 = i * 64 + wave * 8;
            const char* gb = (const char*)(Btg + (size_t)(n0 + r8 + lr) * 1024 + kt * 64) + cl;
            gload_lds16(gb, &Bs[r8 * 64]);
        }
        asm volatile("s_waitcnt vmcnt(0)" ::: "memory");
        __syncthreads();
#pragma unroll
        for (int ks = 0; ks < 2; ++ks) {
            int kb = ks * 64 + (lane >> 4) * 16;
            s16x8 af[4], bf[4];
#pragma unroll
            for (int mf = 0; mf < 4; ++mf) {
                int m = wm * 64 + mf * 16 + (lane & 15);
                af[mf] = *(const s16x8*)&As[m * 64 + ((kb ^ ((m & 7) << 4)) >> 1)];
            }
#pragma unroll
            for (int nf = 0; nf < 4; ++nf) {
                int n = wn * 64 + nf * 16 + (lane & 15);
                bf[nf] = *(const s16x8*)&Bs[n * 64 + ((kb ^ ((n & 7) << 4)) >> 1)];
            }
#pragma unroll
            for (int mf = 0; mf < 4; ++mf)
#pragma unroll
                for (int nf = 0; nf < 4; ++nf)
                    acc[mf][nf] = __builtin_amdgcn_mfma_f32_16x16x32_bf16(af[mf], bf[nf],
                                                                          acc[mf][nf], 0, 0, 0);
        }
    }

    if (n0 >= 2048) {
        // ---- V block: LDS transpose -> VtG[h][v][s], coalesced rows ----
        short* Ls = SMEM;                  // [128][136] padded
        const int h0 = (n0 >> 6) & 15;
        const int b_ = m0 >> 11;
        const int sp0 = m0 & 2047;
#pragma unroll
        for (int half = 0; half < 2; ++half) {
            __syncthreads();
            if ((wm >> 1) == half) {       // this wave's rows lie in this half
#pragma unroll
                for (int nf = 0; nf < 4; ++nf) {
                    int nl = wn * 64 + nf * 16 + (lane & 15);
                    float bb = b2[(n0 + nl) & 1023];
#pragma unroll
                    for (int mf = 0; mf < 4; ++mf) {
#pragma unroll
                        for (int r = 0; r < 4; ++r) {
                            int ml = (wm & 1) * 64 + mf * 16 + (lane >> 4) * 4 + r;
                            Ls[nl * 136 + ml] = f2bf(acc[mf][nf][r] + bb);
                        }
                    }
                }
            }
            __syncthreads();
            int row = tid >> 2, c0 = (tid & 3) * 32;
            short* dst = O2 + ((size_t)(b_ * 1024 + h0 * 64 + row)) * 2048
                         + sp0 + half * 128 + c0;
#pragma unroll
            for (int j = 0; j < 4; ++j)
                *(s16x8*)(dst + j * 8) = *(const s16x8*)&Ls[row * 136 + c0 + j * 8];
        }
    } else {
        // ---- Q/K block: row-major coalesced scatter ----
#pragma unroll
        for (int nf = 0; nf < 4; ++nf) {
            int n = n0 + wn * 64 + nf * 16 + (lane & 15);
            int t = n >> 10;
            int h = (n >> 6) & 15;
            int kk = n & 63;
            const float* bias = (t == 0) ? b0 : b1;
            short* dst = (t == 0) ? O0 : O1;
            float scale = (t == 0) ? 0.1803368851f : 1.0f;  // log2e/8 on Q
            float bb = bias[h * 64 + kk];
#pragma unroll
            for (int mf = 0; mf < 4; ++mf) {
#pragma unroll
                for (int r = 0; r < 4; ++r) {
                    int m = m0 + wm * 64 + mf * 16 + (lane >> 4) * 4 + r;
                    int b_ = m >> 11, sp = m & 2047;
                    float v = (acc[mf][nf][r] + bb) * scale;
                    dst[(((size_t)(b_ * 16 + h)) * 2048 + sp) * 64 + kk] = f2bf(v);
                }
            }
        }
    }
}

// ---------------- causal flash attention: half-K split + 3-stage pipeline ----
// ROUND-21: XCD-aware swizzle (2048 blocks, %8==0, bijective): each XCD gets
// 256 consecutive work items = 8 full heads, so a head's K/V (512KB) stays in
// one L2 (8 x 512KB = 4MB). Otherwise identical to round 19/20 attn: K and V
// both staged via global_load_lds (V from pre-transposed VtG[h][v][s]);
// 4 gload_lds/tile, counted vmcnt(4). Half-K split, fixed-reference exp2
// softmax (ref 0), additive partials, fused dual-strip, pre-permuted K rows,
// l = mfma(P, ones). No min-waves clamp; macros not lambdas.

#define STAGE_K(KT, OFF) do {                                                   \
    _Pragma("unroll")                                                           \
    for (int i_ = 0; i_ < 2; ++i_) {                                            \
        int l_ = wave * 16 + i_ * 8 + lr;  /* LDS row this lane fills */        \
        int gr_ = (((l_ >> 4) & 1) << 5) | (((l_ >> 2) & 3) << 3) |             \
                  (((l_ >> 5) & 1) << 2) | (l_ & 3);  /* permuted K row */      \
        const char* g_ = (const char*)(Kb + base + (size_t)((KT) * 64 + gr_) * 64) + cl; \
        gload_lds16(g_, &KsAll[(OFF) + (wave * 16 + i_ * 8) * 64]);             \
    } } while (0)

#define STAGE_V(KT, OFF) do {                                                   \
    _Pragma("unroll")                                                           \
    for (int i_ = 0; i_ < 2; ++i_) {                                            \
        int v_ = wave * 16 + i_ * 8 + lr;  /* V^T row this lane fills */        \
        const char* g_ = (const char*)(VtG + vgh_ + (size_t)v_ * 2048 + (KT) * 64) + cl; \
        gload_lds16(g_, &VtAll[(OFF) + (wave * 16 + i_ * 8) * 64]);             \
    } } while (0)

#define RAWEXP(X) asm("v_exp_f32 %0, %1" : "=v"(X) : "v"(X))

// Fused dual-strip compute on tile KT. sc[nf][r] holds (exp2 domain)
// S[key = 32*(nf&1) + 8*(lane>>4) + 4*(nf>>1) + r][q = wave*16 + (lane&15)].
#define STRIP2_COMPUTE(KT, OFF) do {                                            \
    f32x4 scL_[4] = {}, scS_[4] = {};                                           \
    __builtin_amdgcn_s_setprio(1);                                              \
    _Pragma("unroll")                                                           \
    for (int ks_ = 0; ks_ < 2; ++ks_) {                                         \
        int kb_ = ks_ * 64 + (lane >> 4) * 16;                                  \
        _Pragma("unroll")                                                       \
        for (int nf_ = 0; nf_ < 4; ++nf_) {                                     \
            int key_ = nf_ * 16 + (lane & 15);                                  \
            s16x8 bf_ = *(const s16x8*)&KsAll[(OFF) + key_ * 64 + ((kb_ ^ ((key_ & 7) << 4)) >> 1)]; \
            scL_[nf_] = __builtin_amdgcn_mfma_f32_16x16x32_bf16(bf_, qL_[ks_], scL_[nf_], 0, 0, 0); \
            scS_[nf_] = __builtin_amdgcn_mfma_f32_16x16x32_bf16(bf_, qS_[ks_], scS_[nf_], 0, 0, 0); \
        }                                                                       \
    }                                                                           \
    __builtin_amdgcn_s_setprio(0);                                              \
    if ((KT) == QTSv_) {  /* S diagonal mask */                                 \
        int qq_ = wave * 16 + (lane & 15);                                      \
        int g8_ = (lane >> 4) * 8;                                              \
        _Pragma("unroll")                                                       \
        for (int nf_ = 0; nf_ < 4; ++nf_) {                                     \
            _Pragma("unroll")                                                   \
            for (int r_ = 0; r_ < 4; ++r_) {                                    \
                int key_ = ((nf_ & 1) << 5) + g8_ + ((nf_ >> 1) << 2) + r_;     \
                if (key_ > qq_) scS_[nf_][r_] = NEG_INF;                        \
            }                                                                   \
        }                                                                       \
    }                                                                           \
    _Pragma("unroll")                                                           \
    for (int nf_ = 0; nf_ < 4; ++nf_)                                           \
        _Pragma("unroll")                                                       \
        for (int r_ = 0; r_ < 4; ++r_) {                                        \
            RAWEXP(scL_[nf_][r_]);                                              \
            RAWEXP(scS_[nf_][r_]);                                              \
        }                                                                       \
    unsigned pdL_[4][2], pdS_[4][2];                                            \
    _Pragma("unroll")                                                           \
    for (int nf_ = 0; nf_ < 4; ++nf_) {                                         \
        asm("v_cvt_pk_bf16_f32 %0, %1, %2"                                      \
            : "=v"(pdL_[nf_][0]) : "v"(scL_[nf_][0]), "v"(scL_[nf_][1]));       \
        asm("v_cvt_pk_bf16_f32 %0, %1, %2"                                      \
            : "=v"(pdL_[nf_][1]) : "v"(scL_[nf_][2]), "v"(scL_[nf_][3]));       \
        asm("v_cvt_pk_bf16_f32 %0, %1, %2"                                      \
            : "=v"(pdS_[nf_][0]) : "v"(scS_[nf_][0]), "v"(scS_[nf_][1]));       \
        asm("v_cvt_pk_bf16_f32 %0, %1, %2"                                      \
            : "=v"(pdS_[nf_][1]) : "v"(scS_[nf_][2]), "v"(scS_[nf_][3]));       \
    }                                                                           \
    __builtin_amdgcn_s_setprio(1);                                              \
    _Pragma("unroll")                                                           \
    for (int ks_ = 0; ks_ < 2; ++ks_) {                                         \
        i32x4 piL_, piS_;                                                       \
        piL_[0] = (int)pdL_[ks_][0]; piL_[1] = (int)pdL_[ks_][1];               \
        piL_[2] = (int)pdL_[ks_ + 2][0]; piL_[3] = (int)pdL_[ks_ + 2][1];       \
        piS_[0] = (int)pdS_[ks_][0]; piS_[1] = (int)pdS_[ks_][1];               \
        piS_[2] = (int)pdS_[ks_ + 2][0]; piS_[3] = (int)pdS_[ks_ + 2][1];       \
        s16x8 paL_ = __builtin_bit_cast(s16x8, piL_);                           \
        s16x8 paS_ = __builtin_bit_cast(s16x8, piS_);                           \
        lsumL_ = __builtin_amdgcn_mfma_f32_16x16x32_bf16(paL_, onesf, lsumL_, 0, 0, 0); \
        lsumS_ = __builtin_amdgcn_mfma_f32_16x16x32_bf16(paS_, onesf, lsumS_, 0, 0, 0); \
        int kb_ = ks_ * 64 + (lane >> 4) * 16;                                  \
        _Pragma("unroll")                                                       \
        for (int nf_ = 0; nf_ < 4; ++nf_) {                                     \
            int v_ = nf_ * 16 + (lane & 15);                                    \
            s16x8 vf_ = *(const s16x8*)&VtAll[(OFF) + v_ * 64 + ((kb_ ^ ((v_ & 7) << 4)) >> 1)]; \
            oL_[nf_] = __builtin_amdgcn_mfma_f32_16x16x32_bf16(paL_, vf_, oL_[nf_], 0, 0, 0); \
            oS_[nf_] = __builtin_amdgcn_mfma_f32_16x16x32_bf16(paS_, vf_, oS_[nf_], 0, 0, 0); \
        }                                                                       \
    }                                                                           \
    __builtin_amdgcn_s_setprio(0);                                              \
    } while (0)

// single-strip compute (L diagonal tile, always masked)
#define STRIP_COMPUTE(QF, O, LSUM, OFF) do {                                    \
    f32x4 sc_[4] = {};                                                          \
    __builtin_amdgcn_s_setprio(1);                                              \
    _Pragma("unroll")                                                           \
    for (int ks_ = 0; ks_ < 2; ++ks_) {                                         \
        int kb_ = ks_ * 64 + (lane >> 4) * 16;                                  \
        _Pragma("unroll")                                                       \
        for (int nf_ = 0; nf_ < 4; ++nf_) {                                     \
            int key_ = nf_ * 16 + (lane & 15);                                  \
            s16x8 bf_ = *(const s16x8*)&KsAll[(OFF) + key_ * 64 + ((kb_ ^ ((key_ & 7) << 4)) >> 1)]; \
            sc_[nf_] = __builtin_amdgcn_mfma_f32_16x16x32_bf16(bf_, QF[ks_], sc_[nf_], 0, 0, 0); \
        }                                                                       \
    }                                                                           \
    __builtin_amdgcn_s_setprio(0);                                              \
    {                                                                           \
        int qq_ = wave * 16 + (lane & 15);                                      \
        int g8_ = (lane >> 4) * 8;                                              \
        _Pragma("unroll")                                                       \
        for (int nf_ = 0; nf_ < 4; ++nf_) {                                     \
            _Pragma("unroll")                                                   \
            for (int r_ = 0; r_ < 4; ++r_) {                                    \
                int key_ = ((nf_ & 1) << 5) + g8_ + ((nf_ >> 1) << 2) + r_;     \
                if (key_ > qq_) sc_[nf_][r_] = NEG_INF;                         \
            }                                                                   \
        }                                                                       \
    }                                                                           \
    _Pragma("unroll")                                                           \
    for (int nf_ = 0; nf_ < 4; ++nf_)                                           \
        _Pragma("unroll")                                                       \
        for (int r_ = 0; r_ < 4; ++r_) RAWEXP(sc_[nf_][r_]);                    \
    unsigned pd_[4][2];                                                         \
    _Pragma("unroll")                                                           \
    for (int nf_ = 0; nf_ < 4; ++nf_) {                                         \
        asm("v_cvt_pk_bf16_f32 %0, %1, %2"                                      \
            : "=v"(pd_[nf_][0]) : "v"(sc_[nf_][0]), "v"(sc_[nf_][1]));          \
        asm("v_cvt_pk_bf16_f32 %0, %1, %2"                                      \
            : "=v"(pd_[nf_][1]) : "v"(sc_[nf_][2]), "v"(sc_[nf_][3]));          \
    }                                                                           \
    __builtin_amdgcn_s_setprio(1);                                              \
    _Pragma("unroll")                                                           \
    for (int ks_ = 0; ks_ < 2; ++ks_) {                                         \
        i32x4 pi_;                                                              \
        pi_[0] = (int)pd_[ks_][0]; pi_[1] = (int)pd_[ks_][1];                   \
        pi_[2] = (int)pd_[ks_ + 2][0]; pi_[3] = (int)pd_[ks_ + 2][1];           \
        s16x8 pa_ = __builtin_bit_cast(s16x8, pi_);                             \
        LSUM = __builtin_amdgcn_mfma_f32_16x16x32_bf16(pa_, onesf, LSUM, 0, 0, 0); \
        int kb_ = ks_ * 64 + (lane >> 4) * 16;                                  \
        _Pragma("unroll")                                                       \
        for (int nf_ = 0; nf_ < 4; ++nf_) {                                     \
            int v_ = nf_ * 16 + (lane & 15);                                    \
            s16x8 vf_ = *(const s16x8*)&VtAll[(OFF) + v_ * 64 + ((kb_ ^ ((v_ & 7) << 4)) >> 1)]; \
            O[nf_] = __builtin_amdgcn_mfma_f32_16x16x32_bf16(pa_, vf_, O[nf_], 0, 0, 0); \
        }                                                                       \
    }                                                                           \
    __builtin_amdgcn_s_setprio(0);                                              \
    } while (0)

// one 3-stage pipeline iteration: stage K+V of t+2 (4 gload_lds, 2 tile-times
// to land), compute tile t, counted vmcnt(4) leaves t+2's loads in flight.
#define ITERB(T) do {                                                           \
    const bool st2_ = ((T) + 2 < hi_);                                          \
    if (st2_) { STAGE_K((T) + 2, off2_); STAGE_V((T) + 2, off2_); }             \
    STRIP2_COMPUTE((T), off0_);                                                 \
    if ((T) + 1 < hi_) {                                                        \
        if (st2_) asm volatile("s_waitcnt vmcnt(4) lgkmcnt(0)" ::: "memory");   \
        else      asm volatile("s_waitcnt vmcnt(0) lgkmcnt(0)" ::: "memory");   \
        __builtin_amdgcn_s_barrier();                                           \
    }                                                                           \
    int tmp_ = off0_; off0_ = off1_; off1_ = off2_; off2_ = tmp_;               \
} while (0)

// partial write: rows SOFF..SOFF+63 of the slot (S strip SOFF=0, L SOFF=64)
#define PEPILOGUE(SOFF, O, LSUM) do {                                           \
    _Pragma("unroll")                                                           \
    for (int r_ = 0; r_ < 4; ++r_) {                                            \
        int row_ = (SOFF) + wave * 16 + (lane >> 4) * 4 + r_;                   \
        if ((lane & 15) == 0) Lp_[row_] = LSUM[r_];                             \
        _Pragma("unroll")                                                       \
        for (int nf_ = 0; nf_ < 4; ++nf_)                                       \
            Op_[row_ * 64 + nf_ * 16 + (lane & 15)] = f2bf(O[nf_][r_]);         \
    } } while (0)

__launch_bounds__(256)
__global__ void attn_fwd(const short* __restrict__ Qb, const short* __restrict__ Kb,
                         const short* __restrict__ VtG, short* __restrict__ Opart,
                         float* __restrict__ Lpart) {
    __shared__ short KsAll[3 * 64 * 64];
    __shared__ short VtAll[3 * 64 * 64];
    const int tid = threadIdx.x, wave = tid >> 6, lane = tid & 63;
    // XCD swizzle: 2048 blocks -> each XCD gets 256 consecutive work items
    // = 8 full heads (head-major within XCD, chunks LPT-ordered within head).
    const int bid = blockIdx.x + 64 * blockIdx.y;          // 0..2047
    const int sb = (bid & 7) * 256 + (bid >> 3);           // bijective (2048%8==0)
    const int hx = sb >> 5;                  // head index b*16+h
    const int y = sb & 31;                   // 0..31
    const int jj = 15 - (y >> 1);            // longest chunks first within head
    const int half = y & 1;
    const int lo_ = half * (jj + 1);
    const int hi_ = lo_ + jj + 1;            // exactly jj+1 tiles per block
    const int QTSv_ = 2 * jj, QTLv_ = 2 * jj + 1;
    const int ND_ = ((hi_ < QTLv_) ? hi_ : QTLv_) - lo_;   // fused dual tiles
    const bool tail_ = (hi_ > QTLv_);        // L diagonal tile in this chunk
    const size_t base = (size_t)hx * 2048 * 64;
    const size_t vgh_ = (size_t)hx * 131072; // VtG head stride 64*2048
    const float NEG_INF = -__builtin_inff();

    const int qrow = wave * 16 + (lane & 15);
    const int qoff = (lane >> 4) * 8;
    const int lr = lane >> 3, cl = ((lane & 7) * 16) ^ (lr << 4);

    const s16x8 onesf = {(short)0x3F80, (short)0x3F80, (short)0x3F80, (short)0x3F80,
                         (short)0x3F80, (short)0x3F80, (short)0x3F80, (short)0x3F80};

    s16x8 qL_[2], qS_[2];
#pragma unroll
    for (int ks = 0; ks < 2; ++ks) {
        qL_[ks] = *(const s16x8*)&Qb[base + (size_t)(QTLv_ * 64 + qrow) * 64 + ks * 32 + qoff];
        qS_[ks] = *(const s16x8*)&Qb[base + (size_t)(QTSv_ * 64 + qrow) * 64 + ks * 32 + qoff];
    }

    f32x4 oL_[4] = {}, oS_[4] = {};
    f32x4 lsumL_ = {}, lsumS_ = {};
    int off0_ = 0, off1_ = 4096, off2_ = 8192;

    // prologue: stage tiles lo and lo+1 (4 gload_lds each); counted wait
    // leaves the lo+1 loads (newest 4) in flight across the barrier.
    STAGE_K(lo_, off0_); STAGE_V(lo_, off0_);
    const bool two_ = (lo_ + 1 < hi_);
    if (two_) {
        STAGE_K(lo_ + 1, off1_); STAGE_V(lo_ + 1, off1_);
        asm volatile("s_waitcnt vmcnt(4)" ::: "memory");
    } else {
        asm volatile("s_waitcnt vmcnt(0)" ::: "memory");
    }
    __builtin_amdgcn_s_barrier();

    for (int t_ = lo_; t_ < lo_ + ND_; ++t_) {
        ITERB(t_);
    }

    if (tail_) {
        STRIP_COMPUTE(qL_, oL_, lsumL_, off0_);
    }

    // additive partial write (fixed-reference softmax => partials just add)
    const int slot_ = (hx * 16 + jj) * 2 + half;
    short* Op_ = Opart + (size_t)slot_ * 8192;
    float* Lp_ = Lpart + (size_t)slot_ * 128;
    PEPILOGUE(0, oS_, lsumS_);
    PEPILOGUE(64, oL_, lsumL_);
}

// combine: Ab = (O_half0 + O_half1) / (l_half0 + l_half1). grid 1024 = hx*16+jj.
__launch_bounds__(256)
__global__ void attn_combine(const short* __restrict__ Opart, const float* __restrict__ Lpart,
                             short* __restrict__ Ab) {
    const int bx = blockIdx.x, t = threadIdx.x;
    const int hx = bx >> 4, jj = bx & 15;
    const int b_ = hx >> 4, h = hx & 15;
    const short* O0 = Opart + (size_t)((hx * 16 + jj) * 2) * 8192;
    const short* O1 = O0 + 8192;
    const float* L0 = Lpart + (size_t)((hx * 16 + jj) * 2) * 128;
    const float* L1 = L0 + 128;
    const int c4 = (t & 15) * 4;
#pragma unroll
    for (int p = 0; p < 8; ++p) {
        int row = (t >> 4) + p * 16;
        float rl = 1.0f / (L0[row] + L1[row]);
        s16x4 a = *(const s16x4*)&O0[row * 64 + c4];
        s16x4 b = *(const s16x4*)&O1[row * 64 + c4];
        s16x4 o;
#pragma unroll
        for (int q = 0; q < 4; ++q) o[q] = f2bf((bf2f(a[q]) + bf2f(b[q])) * rl);
        int qglob = jj * 128 + row;
        *(s16x4*)&Ab[((size_t)(b_ * 2048 + qglob)) * 1024 + h * 64 + c4] = o;
    }
}

// ---------------- launcher ----------------

extern "C" void kernel_launch(void* const* d_in, const int* in_sizes, int n_in,
                              void* d_out, int out_size, void* d_ws, size_t ws_size,
                              hipStream_t stream) {
    const float* X  = (const float*)d_in[0];
    const float* Wq = (const float*)d_in[1];
    const float* bq = (const float*)d_in[2];
    const float* Wk = (const float*)d_in[3];
    const float* bk = (const float*)d_in[4];
    const float* Wv = (const float*)d_in[5];
    const float* bv = (const float*)d_in[6];
    const float* Wo = (const float*)d_in[7];
    const float* bo = (const float*)d_in[8];
    float* out = (float*)d_out;
    char* ws = (char*)d_ws;

    short* Wobt  = (short*)(ws);                  // 2 MB   [lives until GEMM2]
    short* Qb    = (short*)(ws + 2097152);        // 16 MB
    short* Kb    = (short*)(ws + 18874368);       // 16 MB
    short* VtG   = (short*)(ws + 35651584);       // 16 MB  (V transposed [h][v][s])
    short* Ab    = (short*)(ws + 52428800);       // 16 MB
    short* Xb    = (short*)(ws + 69206016);       // 16 MB  [dead after GEMM1]
    short* Opart = (short*)(ws + 69206016);       // 32 MB  (overlay Xb/Wbt)
    short* Wbt   = (short*)(ws + 85983232);       // 6 MB   [dead after GEMM1]
    float* Lpart = (float*)(ws + 102760448);      // 1 MB   -> end ~99 MB

    k_cvt_x<<<2048, 256, 0, stream>>>(X, Xb, 8192 * 1024 / 4);
    k_pack_wqkv_t<<<768, 256, 0, stream>>>(Wq, Wk, Wv, Wbt);
    k_pack_wo_t<<<256, 256, 0, stream>>>(Wo, Wobt);

    gemm_qkv<<<dim3(24, 32), 512, 0, stream>>>(Xb, Wbt, bq, bk, bv, Qb, Kb, VtG);
    attn_fwd<<<dim3(64, 32), 256, 0, stream>>>(Qb, Kb, VtG, Opart, Lpart);
    attn_combine<<<1024, 256, 0, stream>>>(Opart, Lpart, Ab);
    gemm_bf16<1><<<dim3(8, 64), 256, 0, stream>>>(Ab, Wobt, bo, nullptr, nullptr,
                                                  nullptr, nullptr, nullptr, out);
}

// Round 22
// 163.835 us; speedup vs baseline: 1.0625x; 1.0625x over previous
//
#include <hip/hip_runtime.h>
#include <cstdint>
#include <cstddef>

typedef __attribute__((ext_vector_type(4))) float f32x4;
typedef __attribute__((ext_vector_type(8))) short s16x8;
typedef __attribute__((ext_vector_type(4))) short s16x4;
typedef __attribute__((ext_vector_type(4))) int i32x4;

#define DEV __device__ __forceinline__

DEV short f2bf(float f) {
    unsigned u = __builtin_bit_cast(unsigned, f);
    unsigned r = (u + 0x7FFFu + ((u >> 16) & 1u)) >> 16;
    return (short)r;
}

DEV float bf2f(short s) {
    return __builtin_bit_cast(float, ((unsigned)(unsigned short)s) << 16);
}

DEV void gload_lds16(const void* g, void* l) {
    __builtin_amdgcn_global_load_lds(
        (const __attribute__((address_space(1))) unsigned int*)g,
        (__attribute__((address_space(3))) unsigned int*)l, 16, 0, 0);
}

// ---------------- conversion / packing kernels ----------------

__global__ void k_cvt_x(const float* __restrict__ X, short* __restrict__ Xb, int n4) {
    int stride = gridDim.x * blockDim.x;
    for (int i = blockIdx.x * blockDim.x + threadIdx.x; i < n4; i += stride) {
        f32x4 v = *(const f32x4*)&X[i * 4];
        s16x4 s;
#pragma unroll
        for (int j = 0; j < 4; ++j) s[j] = f2bf(v[j]);
        *(s16x4*)&Xb[i * 4] = s;
    }
}

// Coalesced LDS-transpose pack: Wbt[t*1024+h*64+k][d] = W_t[h][d][k].
__global__ void k_pack_wqkv_t(const float* __restrict__ Wq, const float* __restrict__ Wk,
                              const float* __restrict__ Wv, short* __restrict__ Wbt) {
    __shared__ float tileT[64][65];   // [k][d], +1 pad
    const int bx = blockIdx.x, tid = threadIdx.x;
    const int t = bx >> 8, h = (bx >> 4) & 15, dc = bx & 15;
    const float* W = (t == 0) ? Wq : (t == 1) ? Wk : Wv;
    const float* src = W + ((size_t)h * 1024 + dc * 64) * 64;   // contiguous 4096 f32
#pragma unroll
    for (int i = 0; i < 4; ++i) {
        int idx4 = i * 256 + tid;
        f32x4 v = *(const f32x4*)&src[idx4 * 4];
        int flat = idx4 * 4;
        int d = flat >> 6, k0 = flat & 63;
#pragma unroll
        for (int q = 0; q < 4; ++q) tileT[k0 + q][d] = v[q];
    }
    __syncthreads();
    const int k = tid >> 2, d4 = (tid & 3) * 16;
    s16x8 o0, o1;
#pragma unroll
    for (int q = 0; q < 8; ++q) {
        o0[q] = f2bf(tileT[k][d4 + q]);
        o1[q] = f2bf(tileT[k][d4 + 8 + q]);
    }
    size_t c = (size_t)t * 1024 + h * 64 + k;
    *(s16x8*)&Wbt[c * 1024 + dc * 64 + d4] = o0;
    *(s16x8*)&Wbt[c * 1024 + dc * 64 + d4 + 8] = o1;
}

// Coalesced transpose pack: Wobt[n][c] = Wo[c][n]. grid 256 = cchunk x nchunk.
__global__ void k_pack_wo_t(const float* __restrict__ Wo, short* __restrict__ Wobt) {
    __shared__ float tileT[64][65];   // [n][c]
    const int bx = blockIdx.x, tid = threadIdx.x;
    const int c0 = (bx >> 4) * 64, n0 = (bx & 15) * 64;
    const int r = tid >> 2, cch = tid & 3;
#pragma unroll
    for (int it = 0; it < 4; ++it) {
        int colf = cch * 4 + it * 16;
        f32x4 v = *(const f32x4*)&Wo[(size_t)(c0 + r) * 1024 + n0 + colf];
#pragma unroll
        for (int q = 0; q < 4; ++q) tileT[colf + q][r] = v[q];
    }
    __syncthreads();
    const int n = tid >> 2, c4 = (tid & 3) * 16;
    s16x8 o0, o1;
#pragma unroll
    for (int q = 0; q < 8; ++q) {
        o0[q] = f2bf(tileT[n][c4 + q]);
        o1[q] = f2bf(tileT[n][c4 + 8 + q]);
    }
    *(s16x8*)&Wobt[(size_t)(n0 + n) * 1024 + c0 + c4] = o0;
    *(s16x8*)&Wobt[(size_t)(n0 + n) * 1024 + c0 + c4 + 8] = o1;
}

// ---------------- GEMM (128x128, 4 waves): used for the output projection ----

template <int EPI>
__launch_bounds__(256)
__global__ void gemm_bf16(const short* __restrict__ Ag, const short* __restrict__ Btg,
                          const float* __restrict__ b0, const float* __restrict__ b1,
                          const float* __restrict__ b2,
                          short* __restrict__ O0, short* __restrict__ O1, short* __restrict__ O2,
                          float* __restrict__ Of) {
    __shared__ short As[128 * 64];
    __shared__ short Bs[128 * 64];
    const int tid = threadIdx.x;
    const int wave = tid >> 6, lane = tid & 63;
    const int wm = wave >> 1, wn = wave & 1;
    const int m0 = blockIdx.y * 128, n0 = blockIdx.x * 128;

    f32x4 acc[4][4] = {};

    const int lr = lane >> 3;
    const int cb = (lane & 7) * 16;
    const int cl = cb ^ (lr << 4);

    for (int kt = 0; kt < 16; ++kt) {
        __syncthreads();
#pragma unroll
        for (int i = 0; i < 4; ++i) {
            int r8 = wave * 32 + i * 8;
            const char* ga = (const char*)(Ag + (size_t)(m0 + r8 + lr) * 1024 + kt * 64) + cl;
            gload_lds16(ga, &As[r8 * 64]);
            const char* gb = (const char*)(Btg + (size_t)(n0 + r8 + lr) * 1024 + kt * 64) + cl;
            gload_lds16(gb, &Bs[r8 * 64]);
        }
        asm volatile("s_waitcnt vmcnt(0)" ::: "memory");
        __syncthreads();
#pragma unroll
        for (int ks = 0; ks < 2; ++ks) {
            int kb = ks * 64 + (lane >> 4) * 16;
            s16x8 af[4], bf[4];
#pragma unroll
            for (int mf = 0; mf < 4; ++mf) {
                int m = wm * 64 + mf * 16 + (lane & 15);
                af[mf] = *(const s16x8*)&As[m * 64 + ((kb ^ ((m & 7) << 4)) >> 1)];
            }
#pragma unroll
            for (int nf = 0; nf < 4; ++nf) {
                int n = wn * 64 + nf * 16 + (lane & 15);
                bf[nf] = *(const s16x8*)&Bs[n * 64 + ((kb ^ ((n & 7) << 4)) >> 1)];
            }
#pragma unroll
            for (int mf = 0; mf < 4; ++mf)
#pragma unroll
                for (int nf = 0; nf < 4; ++nf)
                    acc[mf][nf] = __builtin_amdgcn_mfma_f32_16x16x32_bf16(af[mf], bf[nf],
                                                                          acc[mf][nf], 0, 0, 0);
        }
    }

    if (EPI == 0) {
#pragma unroll
        for (int nf = 0; nf < 4; ++nf) {
            int n = n0 + wn * 64 + nf * 16 + (lane & 15);
            int t = n >> 10;
            int h = (n >> 6) & 15;
            int kk = n & 63;
            const float* bias = (t == 0) ? b0 : (t == 1) ? b1 : b2;
            short* dst = (t == 0) ? O0 : (t == 1) ? O1 : O2;
            float scale = (t == 0) ? 0.1803368851f : 1.0f;
            float bb = bias[h * 64 + kk];
#pragma unroll
            for (int mf = 0; mf < 4; ++mf) {
#pragma unroll
                for (int r = 0; r < 4; ++r) {
                    int m = m0 + wm * 64 + mf * 16 + (lane >> 4) * 4 + r;
                    int b_ = m >> 11, sp = m & 2047;
                    float v = (acc[mf][nf][r] + bb) * scale;
                    dst[(((size_t)(b_ * 16 + h)) * 2048 + sp) * 64 + kk] = f2bf(v);
                }
            }
        }
    } else {
#pragma unroll
        for (int nf = 0; nf < 4; ++nf) {
            int n = n0 + wn * 64 + nf * 16 + (lane & 15);
            float bb = b0[n];
#pragma unroll
            for (int mf = 0; mf < 4; ++mf) {
#pragma unroll
                for (int r = 0; r < 4; ++r) {
                    int m = m0 + wm * 64 + mf * 16 + (lane >> 4) * 4 + r;
                    Of[(size_t)m * 1024 + n] = acc[mf][nf][r] + bb;
                }
            }
        }
    }
}

// ---------------- QKV GEMM: 256x128 tile, 512 threads (8 waves, 4m x 2n) ----
// ROUND-22: reverted round-21's XCD swizzle — it improved L2 locality (FETCH
// 39->25MB) but destroyed the LPT dispatch order, costing ~10us net. Linear
// blockIdx mapping (round 20, best measured: 163.98us total).
// V-region blocks (n0 >= 2048) transpose output through LDS -> coalesced
// VtG[h][v][s] rows. NO min-waves clamp (spilled 3x: rounds 2-3, 16).

__launch_bounds__(512)
__global__ void gemm_qkv(const short* __restrict__ Ag, const short* __restrict__ Btg,
                         const float* __restrict__ b0, const float* __restrict__ b1,
                         const float* __restrict__ b2,
                         short* __restrict__ O0, short* __restrict__ O1,
                         short* __restrict__ O2) {
    __shared__ short SMEM[256 * 64 + 128 * 64];   // 48 KB: As | Bs
    short* As = SMEM;
    short* Bs = SMEM + 256 * 64;
    const int tid = threadIdx.x;
    const int wave = tid >> 6, lane = tid & 63;
    const int wm = wave >> 1, wn = wave & 1;   // 4m x 2n
    const int m0 = blockIdx.y * 256, n0 = blockIdx.x * 128;

    f32x4 acc[4][4] = {};

    const int lr = lane >> 3;
    const int cb = (lane & 7) * 16;
    const int cl = cb ^ (lr << 4);

    for (int kt = 0; kt < 16; ++kt) {
        __syncthreads();
#pragma unroll
        for (int i = 0; i < 4; ++i) {
            int r8 = i * 64 + wave * 8;
            const char* ga = (const char*)(Ag + (size_t)(m0 + r8 + lr) * 1024 + kt * 64) + cl;
            gload_lds16(ga, &As[r8 * 64]);
        }
#pragma unroll
        for (int i = 0; i < 2; ++i) {
            int r8 = i * 64 + wave * 8;
            const char* gb = (const char*)(Btg + (size_t)(n0 + r8 + lr) * 1024 + kt * 64) + cl;
            gload_lds16(gb, &Bs[r8 * 64]);
        }
        asm volatile("s_waitcnt vmcnt(0)" ::: "memory");
        __syncthreads();
#pragma unroll
        for (int ks = 0; ks < 2; ++ks) {
            int kb = ks * 64 + (lane >> 4) * 16;
            s16x8 af[4], bf[4];
#pragma unroll
            for (int mf = 0; mf < 4; ++mf) {
                int m = wm * 64 + mf * 16 + (lane & 15);
                af[mf] = *(const s16x8*)&As[m * 64 + ((kb ^ ((m & 7) << 4)) >> 1)];
            }
#pragma unroll
            for (int nf = 0; nf < 4; ++nf) {
                int n = wn * 64 + nf * 16 + (lane & 15);
                bf[nf] = *(const s16x8*)&Bs[n * 64 + ((kb ^ ((n & 7) << 4)) >> 1)];
            }
#pragma unroll
            for (int mf = 0; mf < 4; ++mf)
#pragma unroll
                for (int nf = 0; nf < 4; ++nf)
                    acc[mf][nf] = __builtin_amdgcn_mfma_f32_16x16x32_bf16(af[mf], bf[nf],
                                                                          acc[mf][nf], 0, 0, 0);
        }
    }

    if (n0 >= 2048) {
        // ---- V block: LDS transpose -> VtG[h][v][s], coalesced rows ----
        short* Ls = SMEM;                  // [128][136] padded
        const int h0 = (n0 >> 6) & 15;
        const int b_ = m0 >> 11;
        const int sp0 = m0 & 2047;
#pragma unroll
        for (int half = 0; half < 2; ++half) {
            __syncthreads();
            if ((wm >> 1) == half) {       // this wave's rows lie in this half
#pragma unroll
                for (int nf = 0; nf < 4; ++nf) {
                    int nl = wn * 64 + nf * 16 + (lane & 15);
                    float bb = b2[(n0 + nl) & 1023];
#pragma unroll
                    for (int mf = 0; mf < 4; ++mf) {
#pragma unroll
                        for (int r = 0; r < 4; ++r) {
                            int ml = (wm & 1) * 64 + mf * 16 + (lane >> 4) * 4 + r;
                            Ls[nl * 136 + ml] = f2bf(acc[mf][nf][r] + bb);
                        }
                    }
                }
            }
            __syncthreads();
            int row = tid >> 2, c0 = (tid & 3) * 32;
            short* dst = O2 + ((size_t)(b_ * 1024 + h0 * 64 + row)) * 2048
                         + sp0 + half * 128 + c0;
#pragma unroll
            for (int j = 0; j < 4; ++j)
                *(s16x8*)(dst + j * 8) = *(const s16x8*)&Ls[row * 136 + c0 + j * 8];
        }
    } else {
        // ---- Q/K block: row-major coalesced scatter ----
#pragma unroll
        for (int nf = 0; nf < 4; ++nf) {
            int n = n0 + wn * 64 + nf * 16 + (lane & 15);
            int t = n >> 10;
            int h = (n >> 6) & 15;
            int kk = n & 63;
            const float* bias = (t == 0) ? b0 : b1;
            short* dst = (t == 0) ? O0 : O1;
            float scale = (t == 0) ? 0.1803368851f : 1.0f;  // log2e/8 on Q
            float bb = bias[h * 64 + kk];
#pragma unroll
            for (int mf = 0; mf < 4; ++mf) {
#pragma unroll
                for (int r = 0; r < 4; ++r) {
                    int m = m0 + wm * 64 + mf * 16 + (lane >> 4) * 4 + r;
                    int b_ = m >> 11, sp = m & 2047;
                    float v = (acc[mf][nf][r] + bb) * scale;
                    dst[(((size_t)(b_ * 16 + h)) * 2048 + sp) * 64 + kk] = f2bf(v);
                }
            }
        }
    }
}

// ---------------- causal flash attention: half-K split + 3-stage pipeline ----
// Round-20 attn (best measured): K and V both staged via global_load_lds (V
// from pre-transposed VtG[h][v][s]); 4 gload_lds/tile, counted vmcnt(4).
// Half-K split grid (64,32) with LPT dispatch (y=0 longest), fixed-reference
// exp2 softmax (ref 0), additive partials, fused dual-strip, pre-permuted K
// rows (P in registers), l = mfma(P, ones). No min-waves clamp; macros not
// lambdas; linear blockIdx (round-21 XCD swizzle broke LPT, reverted).

#define STAGE_K(KT, OFF) do {                                                   \
    _Pragma("unroll")                                                           \
    for (int i_ = 0; i_ < 2; ++i_) {                                            \
        int l_ = wave * 16 + i_ * 8 + lr;  /* LDS row this lane fills */        \
        int gr_ = (((l_ >> 4) & 1) << 5) | (((l_ >> 2) & 3) << 3) |             \
                  (((l_ >> 5) & 1) << 2) | (l_ & 3);  /* permuted K row */      \
        const char* g_ = (const char*)(Kb + base + (size_t)((KT) * 64 + gr_) * 64) + cl; \
        gload_lds16(g_, &KsAll[(OFF) + (wave * 16 + i_ * 8) * 64]);             \
    } } while (0)

#define STAGE_V(KT, OFF) do {                                                   \
    _Pragma("unroll")                                                           \
    for (int i_ = 0; i_ < 2; ++i_) {                                            \
        int v_ = wave * 16 + i_ * 8 + lr;  /* V^T row this lane fills */        \
        const char* g_ = (const char*)(VtG + vgh_ + (size_t)v_ * 2048 + (KT) * 64) + cl; \
        gload_lds16(g_, &VtAll[(OFF) + (wave * 16 + i_ * 8) * 64]);             \
    } } while (0)

#define RAWEXP(X) asm("v_exp_f32 %0, %1" : "=v"(X) : "v"(X))

// Fused dual-strip compute on tile KT. sc[nf][r] holds (exp2 domain)
// S[key = 32*(nf&1) + 8*(lane>>4) + 4*(nf>>1) + r][q = wave*16 + (lane&15)].
#define STRIP2_COMPUTE(KT, OFF) do {                                            \
    f32x4 scL_[4] = {}, scS_[4] = {};                                           \
    __builtin_amdgcn_s_setprio(1);                                              \
    _Pragma("unroll")                                                           \
    for (int ks_ = 0; ks_ < 2; ++ks_) {                                         \
        int kb_ = ks_ * 64 + (lane >> 4) * 16;                                  \
        _Pragma("unroll")                                                       \
        for (int nf_ = 0; nf_ < 4; ++nf_) {                                     \
            int key_ = nf_ * 16 + (lane & 15);                                  \
            s16x8 bf_ = *(const s16x8*)&KsAll[(OFF) + key_ * 64 + ((kb_ ^ ((key_ & 7) << 4)) >> 1)]; \
            scL_[nf_] = __builtin_amdgcn_mfma_f32_16x16x32_bf16(bf_, qL_[ks_], scL_[nf_], 0, 0, 0); \
            scS_[nf_] = __builtin_amdgcn_mfma_f32_16x16x32_bf16(bf_, qS_[ks_], scS_[nf_], 0, 0, 0); \
        }                                                                       \
    }                                                                           \
    __builtin_amdgcn_s_setprio(0);                                              \
    if ((KT) == QTSv_) {  /* S diagonal mask */                                 \
        int qq_ = wave * 16 + (lane & 15);                                      \
        int g8_ = (lane >> 4) * 8;                                              \
        _Pragma("unroll")                                                       \
        for (int nf_ = 0; nf_ < 4; ++nf_) {                                     \
            _Pragma("unroll")                                                   \
            for (int r_ = 0; r_ < 4; ++r_) {                                    \
                int key_ = ((nf_ & 1) << 5) + g8_ + ((nf_ >> 1) << 2) + r_;     \
                if (key_ > qq_) scS_[nf_][r_] = NEG_INF;                        \
            }                                                                   \
        }                                                                       \
    }                                                                           \
    _Pragma("unroll")                                                           \
    for (int nf_ = 0; nf_ < 4; ++nf_)                                           \
        _Pragma("unroll")                                                       \
        for (int r_ = 0; r_ < 4; ++r_) {                                        \
            RAWEXP(scL_[nf_][r_]);                                              \
            RAWEXP(scS_[nf_][r_]);                                              \
        }                                                                       \
    unsigned pdL_[4][2], pdS_[4][2];                                            \
    _Pragma("unroll")                                                           \
    for (int nf_ = 0; nf_ < 4; ++nf_) {                                         \
        asm("v_cvt_pk_bf16_f32 %0, %1, %2"                                      \
            : "=v"(pdL_[nf_][0]) : "v"(scL_[nf_][0]), "v"(scL_[nf_][1]));       \
        asm("v_cvt_pk_bf16_f32 %0, %1, %2"                                      \
            : "=v"(pdL_[nf_][1]) : "v"(scL_[nf_][2]), "v"(scL_[nf_][3]));       \
        asm("v_cvt_pk_bf16_f32 %0, %1, %2"                                      \
            : "=v"(pdS_[nf_][0]) : "v"(scS_[nf_][0]), "v"(scS_[nf_][1]));       \
        asm("v_cvt_pk_bf16_f32 %0, %1, %2"                                      \
            : "=v"(pdS_[nf_][1]) : "v"(scS_[nf_][2]), "v"(scS_[nf_][3]));       \
    }                                                                           \
    __builtin_amdgcn_s_setprio(1);                                              \
    _Pragma("unroll")                                                           \
    for (int ks_ = 0; ks_ < 2; ++ks_) {                                         \
        i32x4 piL_, piS_;                                                       \
        piL_[0] = (int)pdL_[ks_][0]; piL_[1] = (int)pdL_[ks_][1];               \
        piL_[2] = (int)pdL_[ks_ + 2][0]; piL_[3] = (int)pdL_[ks_ + 2][1];       \
        piS_[0] = (int)pdS_[ks_][0]; piS_[1] = (int)pdS_[ks_][1];               \
        piS_[2] = (int)pdS_[ks_ + 2][0]; piS_[3] = (int)pdS_[ks_ + 2][1];       \
        s16x8 paL_ = __builtin_bit_cast(s16x8, piL_);                           \
        s16x8 paS_ = __builtin_bit_cast(s16x8, piS_);                           \
        lsumL_ = __builtin_amdgcn_mfma_f32_16x16x32_bf16(paL_, onesf, lsumL_, 0, 0, 0); \
        lsumS_ = __builtin_amdgcn_mfma_f32_16x16x32_bf16(paS_, onesf, lsumS_, 0, 0, 0); \
        int kb_ = ks_ * 64 + (lane >> 4) * 16;                                  \
        _Pragma("unroll")                                                       \
        for (int nf_ = 0; nf_ < 4; ++nf_) {                                     \
            int v_ = nf_ * 16 + (lane & 15);                                    \
            s16x8 vf_ = *(const s16x8*)&VtAll[(OFF) + v_ * 64 + ((kb_ ^ ((v_ & 7) << 4)) >> 1)]; \
            oL_[nf_] = __builtin_amdgcn_mfma_f32_16x16x32_bf16(paL_, vf_, oL_[nf_], 0, 0, 0); \
            oS_[nf_] = __builtin_amdgcn_mfma_f32_16x16x32_bf16(paS_, vf_, oS_[nf_], 0, 0, 0); \
        }                                                                       \
    }                                                                           \
    __builtin_amdgcn_s_setprio(0);                                              \
    } while (0)

// single-strip compute (L diagonal tile, always masked)
#define STRIP_COMPUTE(QF, O, LSUM, OFF) do {                                    \
    f32x4 sc_[4] = {};                                                          \
    __builtin_amdgcn_s_setprio(1);                                              \
    _Pragma("unroll")                                                           \
    for (int ks_ = 0; ks_ < 2; ++ks_) {                                         \
        int kb_ = ks_ * 64 + (lane >> 4) * 16;                                  \
        _Pragma("unroll")                                                       \
        for (int nf_ = 0; nf_ < 4; ++nf_) {                                     \
            int key_ = nf_ * 16 + (lane & 15);                                  \
            s16x8 bf_ = *(const s16x8*)&KsAll[(OFF) + key_ * 64 + ((kb_ ^ ((key_ & 7) << 4)) >> 1)]; \
            sc_[nf_] = __builtin_amdgcn_mfma_f32_16x16x32_bf16(bf_, QF[ks_], sc_[nf_], 0, 0, 0); \
        }                                                                       \
    }                                                                           \
    __builtin_amdgcn_s_setprio(0);                                              \
    {                                                                           \
        int qq_ = wave * 16 + (lane & 15);                                      \
        int g8_ = (lane >> 4) * 8;                                              \
        _Pragma("unroll")                                                       \
        for (int nf_ = 0; nf_ < 4; ++nf_) {                                     \
            _Pragma("unroll")                                                   \
            for (int r_ = 0; r_ < 4; ++r_) {                                    \
                int key_ = ((nf_ & 1) << 5) + g8_ + ((nf_ >> 1) << 2) + r_;     \
                if (key_ > qq_) sc_[nf_][r_] = NEG_INF;                         \
            }                                                                   \
        }                                                                       \
    }                                                                           \
    _Pragma("unroll")                                                           \
    for (int nf_ = 0; nf_ < 4; ++nf_)                                           \
        _Pragma("unroll")                                                       \
        for (int r_ = 0; r_ < 4; ++r_) RAWEXP(sc_[nf_][r_]);                    \
    unsigned pd_[4][2];                                                         \
    _Pragma("unroll")                                                           \
    for (int nf_ = 0; nf_ < 4; ++nf_) {                                         \
        asm("v_cvt_pk_bf16_f32 %0, %1, %2"                                      \
            : "=v"(pd_[nf_][0]) : "v"(sc_[nf_][0]), "v"(sc_[nf_][1]));          \
        asm("v_cvt_pk_bf16_f32 %0, %1, %2"                                      \
            : "=v"(pd_[nf_][1]) : "v"(sc_[nf_][2]), "v"(sc_[nf_][3]));          \
    }                                                                           \
    __builtin_amdgcn_s_setprio(1);                                              \
    _Pragma("unroll")                                                           \
    for (int ks_ = 0; ks_ < 2; ++ks_) {                                         \
        i32x4 pi_;                                                              \
        pi_[0] = (int)pd_[ks_][0]; pi_[1] = (int)pd_[ks_][1];                   \
        pi_[2] = (int)pd_[ks_ + 2][0]; pi_[3] = (int)pd_[ks_ + 2][1];           \
        s16x8 pa_ = __builtin_bit_cast(s16x8, pi_);                             \
        LSUM = __builtin_amdgcn_mfma_f32_16x16x32_bf16(pa_, onesf, LSUM, 0, 0, 0); \
        int kb_ = ks_ * 64 + (lane >> 4) * 16;                                  \
        _Pragma("unroll")                                                       \
        for (int nf_ = 0; nf_ < 4; ++nf_) {                                     \
            int v_ = nf_ * 16 + (lane & 15);                                    \
            s16x8 vf_ = *(const s16x8*)&VtAll[(OFF) + v_ * 64 + ((kb_ ^ ((v_ & 7) << 4)) >> 1)]; \
            O[nf_] = __builtin_amdgcn_mfma_f32_16x16x32_bf16(pa_, vf_, O[nf_], 0, 0, 0); \
        }                                                                       \
    }                                                                           \
    __builtin_amdgcn_s_setprio(0);                                              \
    } while (0)

// one 3-stage pipeline iteration: stage K+V of t+2 (4 gload_lds, 2 tile-times
// to land), compute tile t, counted vmcnt(4) leaves t+2's loads in flight.
#define ITERB(T) do {                                                           \
    const bool st2_ = ((T) + 2 < hi_);                                          \
    if (st2_) { STAGE_K((T) + 2, off2_); STAGE_V((T) + 2, off2_); }             \
    STRIP2_COMPUTE((T), off0_);                                                 \
    if ((T) + 1 < hi_) {                                                        \
        if (st2_) asm volatile("s_waitcnt vmcnt(4) lgkmcnt(0)" ::: "memory");   \
        else      asm volatile("s_waitcnt vmcnt(0) lgkmcnt(0)" ::: "memory");   \
        __builtin_amdgcn_s_barrier();                                           \
    }                                                                           \
    int tmp_ = off0_; off0_ = off1_; off1_ = off2_; off2_ = tmp_;               \
} while (0)

// partial write: rows SOFF..SOFF+63 of the slot (S strip SOFF=0, L SOFF=64)
#define PEPILOGUE(SOFF, O, LSUM) do {                                           \
    _Pragma("unroll")                                                           \
    for (int r_ = 0; r_ < 4; ++r_) {                                            \
        int row_ = (SOFF) + wave * 16 + (lane >> 4) * 4 + r_;                   \
        if ((lane & 15) == 0) Lp_[row_] = LSUM[r_];                             \
        _Pragma("unroll")                                                       \
        for (int nf_ = 0; nf_ < 4; ++nf_)                                       \
            Op_[row_ * 64 + nf_ * 16 + (lane & 15)] = f2bf(O[nf_][r_]);         \
    } } while (0)

__launch_bounds__(256)
__global__ void attn_fwd(const short* __restrict__ Qb, const short* __restrict__ Kb,
                         const short* __restrict__ VtG, short* __restrict__ Opart,
                         float* __restrict__ Lpart) {
    __shared__ short KsAll[3 * 64 * 64];
    __shared__ short VtAll[3 * 64 * 64];
    const int tid = threadIdx.x, wave = tid >> 6, lane = tid & 63;
    const int hx = blockIdx.x;               // head index b*16+h
    const int y = blockIdx.y;                // 0..31
    const int jj = 15 - (y >> 1);            // longest chunks dispatched first
    const int half = y & 1;
    const int lo_ = half * (jj + 1);
    const int hi_ = lo_ + jj + 1;            // exactly jj+1 tiles per block
    const int QTSv_ = 2 * jj, QTLv_ = 2 * jj + 1;
    const int ND_ = ((hi_ < QTLv_) ? hi_ : QTLv_) - lo_;   // fused dual tiles
    const bool tail_ = (hi_ > QTLv_);        // L diagonal tile in this chunk
    const size_t base = (size_t)hx * 2048 * 64;
    const size_t vgh_ = (size_t)hx * 131072; // VtG head stride 64*2048
    const float NEG_INF = -__builtin_inff();

    const int qrow = wave * 16 + (lane & 15);
    const int qoff = (lane >> 4) * 8;
    const int lr = lane >> 3, cl = ((lane & 7) * 16) ^ (lr << 4);

    const s16x8 onesf = {(short)0x3F80, (short)0x3F80, (short)0x3F80, (short)0x3F80,
                         (short)0x3F80, (short)0x3F80, (short)0x3F80, (short)0x3F80};

    s16x8 qL_[2], qS_[2];
#pragma unroll
    for (int ks = 0; ks < 2; ++ks) {
        qL_[ks] = *(const s16x8*)&Qb[base + (size_t)(QTLv_ * 64 + qrow) * 64 + ks * 32 + qoff];
        qS_[ks] = *(const s16x8*)&Qb[base + (size_t)(QTSv_ * 64 + qrow) * 64 + ks * 32 + qoff];
    }

    f32x4 oL_[4] = {}, oS_[4] = {};
    f32x4 lsumL_ = {}, lsumS_ = {};
    int off0_ = 0, off1_ = 4096, off2_ = 8192;

    // prologue: stage tiles lo and lo+1 (4 gload_lds each); counted wait
    // leaves the lo+1 loads (newest 4) in flight across the barrier.
    STAGE_K(lo_, off0_); STAGE_V(lo_, off0_);
    const bool two_ = (lo_ + 1 < hi_);
    if (two_) {
        STAGE_K(lo_ + 1, off1_); STAGE_V(lo_ + 1, off1_);
        asm volatile("s_waitcnt vmcnt(4)" ::: "memory");
    } else {
        asm volatile("s_waitcnt vmcnt(0)" ::: "memory");
    }
    __builtin_amdgcn_s_barrier();

    for (int t_ = lo_; t_ < lo_ + ND_; ++t_) {
        ITERB(t_);
    }

    if (tail_) {
        STRIP_COMPUTE(qL_, oL_, lsumL_, off0_);
    }

    // additive partial write (fixed-reference softmax => partials just add)
    const int slot_ = (hx * 16 + jj) * 2 + half;
    short* Op_ = Opart + (size_t)slot_ * 8192;
    float* Lp_ = Lpart + (size_t)slot_ * 128;
    PEPILOGUE(0, oS_, lsumS_);
    PEPILOGUE(64, oL_, lsumL_);
}

// combine: Ab = (O_half0 + O_half1) / (l_half0 + l_half1). grid 1024 = hx*16+jj.
__launch_bounds__(256)
__global__ void attn_combine(const short* __restrict__ Opart, const float* __restrict__ Lpart,
                             short* __restrict__ Ab) {
    const int bx = blockIdx.x, t = threadIdx.x;
    const int hx = bx >> 4, jj = bx & 15;
    const int b_ = hx >> 4, h = hx & 15;
    const short* O0 = Opart + (size_t)((hx * 16 + jj) * 2) * 8192;
    const short* O1 = O0 + 8192;
    const float* L0 = Lpart + (size_t)((hx * 16 + jj) * 2) * 128;
    const float* L1 = L0 + 128;
    const int c4 = (t & 15) * 4;
#pragma unroll
    for (int p = 0; p < 8; ++p) {
        int row = (t >> 4) + p * 16;
        float rl = 1.0f / (L0[row] + L1[row]);
        s16x4 a = *(const s16x4*)&O0[row * 64 + c4];
        s16x4 b = *(const s16x4*)&O1[row * 64 + c4];
        s16x4 o;
#pragma unroll
        for (int q = 0; q < 4; ++q) o[q] = f2bf((bf2f(a[q]) + bf2f(b[q])) * rl);
        int qglob = jj * 128 + row;
        *(s16x4*)&Ab[((size_t)(b_ * 2048 + qglob)) * 1024 + h * 64 + c4] = o;
    }
}

// ---------------- launcher ----------------

extern "C" void kernel_launch(void* const* d_in, const int* in_sizes, int n_in,
                              void* d_out, int out_size, void* d_ws, size_t ws_size,
                              hipStream_t stream) {
    const float* X  = (const float*)d_in[0];
    const float* Wq = (const float*)d_in[1];
    const float* bq = (const float*)d_in[2];
    const float* Wk = (const float*)d_in[3];
    const float* bk = (const float*)d_in[4];
    const float* Wv = (const float*)d_in[5];
    const float* bv = (const float*)d_in[6];
    const float* Wo = (const float*)d_in[7];
    const float* bo = (const float*)d_in[8];
    float* out = (float*)d_out;
    char* ws = (char*)d_ws;

    short* Wobt  = (short*)(ws);                  // 2 MB   [lives until GEMM2]
    short* Qb    = (short*)(ws + 2097152);        // 16 MB
    short* Kb    = (short*)(ws + 18874368);       // 16 MB
    short* VtG   = (short*)(ws + 35651584);       // 16 MB  (V transposed [h][v][s])
    short* Ab    = (short*)(ws + 52428800);       // 16 MB
    short* Xb    = (short*)(ws + 69206016);       // 16 MB  [dead after GEMM1]
    short* Opart = (short*)(ws + 69206016);       // 32 MB  (overlay Xb/Wbt)
    short* Wbt   = (short*)(ws + 85983232);       // 6 MB   [dead after GEMM1]
    float* Lpart = (float*)(ws + 102760448);      // 1 MB   -> end ~99 MB

    k_cvt_x<<<2048, 256, 0, stream>>>(X, Xb, 8192 * 1024 / 4);
    k_pack_wqkv_t<<<768, 256, 0, stream>>>(Wq, Wk, Wv, Wbt);
    k_pack_wo_t<<<256, 256, 0, stream>>>(Wo, Wobt);

    gemm_qkv<<<dim3(24, 32), 512, 0, stream>>>(Xb, Wbt, bq, bk, bv, Qb, Kb, VtG);
    attn_fwd<<<dim3(64, 32), 256, 0, stream>>>(Qb, Kb, VtG, Opart, Lpart);
    attn_combine<<<1024, 256, 0, stream>>>(Opart, Lpart, Ab);
    gemm_bf16<1><<<dim3(8, 64), 256, 0, stream>>>(Ab, Wobt, bo, nullptr, nullptr,
                                                  nullptr, nullptr, nullptr, out);
}